// Round 2
// baseline (774.492 us; speedup 1.0000x reference)
//
#include <hip/hip_runtime.h>

// Problem constants (fixed by setup_inputs)
#define NT   32768      // B*T tokens
#define NV   32         // V
#define DI   64         // I == H
#define VI   2048       // V*I

typedef __attribute__((ext_vector_type(8)))  short short8;    // 8 bf16 (4 VGPRs)
typedef __attribute__((ext_vector_type(16))) float floatx16;  // MFMA 32x32 acc

#define MFMA32(a,b,c) __builtin_amdgcn_mfma_f32_32x32x16_bf16(a, b, c, 0, 0, 0)

// ---- workspace layout (bytes) ----
#define WS_S      0                  // fp32 [NT][64]  (skip|elu(h1))      8,388,608
#define WS_WBUF   8388608            // fp32 [NT][32]  softmax weights     4,194,304
#define WS_WCOMBT 12582912           // bf16 [64][2048]                      262,144
#define WS_WAV    12845056           // bf16 [32][192][88] W1a+Wca         1,081,344
#define WS_WC2    13926400           // fp32 [32][64]  folded wg W2@Wg         8,192
#define WS_BC2    13934592           // fp32 [64]                               256

static __device__ __forceinline__ unsigned short f2bf(float f) {
    union { float f; unsigned u; } v; v.f = f;
    unsigned r = v.u + 0x7FFFu + ((v.u >> 16) & 1u);   // RNE
    return (unsigned short)(r >> 16);
}
static __device__ __forceinline__ unsigned pk2bf(float lo, float hi) {
    return (unsigned)f2bf(lo) | ((unsigned)f2bf(hi) << 16);
}
static __device__ __forceinline__ float elu1(float v) {
    return (v > 0.f) ? v : (__expf(v) - 1.f);
}
static __device__ __forceinline__ float bflo(unsigned v) {
    union { unsigned u; float f; } t; t.u = v << 16; return t.f;
}
static __device__ __forceinline__ float bfhi(unsigned v) {
    union { unsigned u; float f; } t; t.u = v & 0xFFFF0000u; return t.f;
}

// ============================================================================
// K0: weight prep.
//  WcombT[n][k] = n<32 ? Ws[k][n] : W1[k][n-32]           (bf16, A of k1)
//  wAv[v][192][88]: rows 0..63  = W1^T (row=h, col=i, col64=b1)
//                   rows 64..191 = Wc^T (row=n out of g, col=j h1-idx, col64=bc)
//                   where Wc = v_W2 @ v_Wg, bc = v_b2 @ v_Wg + v_bg  (FOLDED)
//  Wc2[j][n] = wg_W2 @ wg_Wg  (fp32), bc2 = wg_b2 @ wg_Wg + wg_bg   (FOLDED)
// ============================================================================
__global__ void k0_prep(const float* __restrict__ wg_W1, const float* __restrict__ wg_Ws,
                        const float* __restrict__ wg_W2, const float* __restrict__ wg_b2,
                        const float* __restrict__ wg_Wg, const float* __restrict__ wg_bg,
                        const float* __restrict__ v_W1, const float* __restrict__ v_b1,
                        const float* __restrict__ v_W2, const float* __restrict__ v_b2,
                        const float* __restrict__ v_Wg, const float* __restrict__ v_bg,
                        unsigned short* __restrict__ WcombT, unsigned short* __restrict__ wAv,
                        float* __restrict__ Wc2, float* __restrict__ bc2) {
    int tid = blockIdx.x * blockDim.x + threadIdx.x;
    int np  = gridDim.x * blockDim.x;
    // A: WcombT
    for (int i = tid; i < 64 * 2048; i += np) {
        int n = i >> 11, k = i & 2047;
        float val = (n < 32) ? wg_Ws[k * 32 + n] : wg_W1[k * 32 + (n - 32)];
        WcombT[i] = f2bf(val);
    }
    // B: wAv W1 rows
    for (int i = tid; i < 32 * 64 * 88; i += np) {
        int v  = i / (64 * 88);
        int rm = i - v * (64 * 88);
        int h  = rm / 88, c = rm - h * 88;
        float val = 0.f;
        if (c < 64)       val = v_W1[(v * 64 + c) * 64 + h];
        else if (c == 64) val = v_b1[v * 64 + h];
        wAv[v * 16896 + h * 88 + c] = f2bf(val);
    }
    // C: wAv Wc rows (fold W2@Wg)
    for (int i = tid; i < 32 * 128 * 88; i += np) {
        int v  = i / (128 * 88);
        int rm = i - v * (128 * 88);
        int n  = rm / 88, c = rm - n * 88;
        float acc = 0.f;
        if (c < 64) {
            #pragma unroll 8
            for (int k = 0; k < 64; ++k)
                acc += v_W2[(v * 64 + c) * 64 + k] * v_Wg[(v * 64 + k) * 128 + n];
        } else if (c == 64) {
            #pragma unroll 8
            for (int k = 0; k < 64; ++k)
                acc += v_b2[v * 64 + k] * v_Wg[(v * 64 + k) * 128 + n];
            acc += v_bg[v * 128 + n];
        }
        wAv[v * 16896 + (64 + n) * 88 + c] = f2bf(acc);
    }
    // D: Wc2 / bc2
    for (int i = tid; i < 32 * 64 + 64; i += np) {
        if (i < 2048) {
            int j = i >> 6, n = i & 63;
            float acc = 0.f;
            #pragma unroll 8
            for (int k = 0; k < 32; ++k) acc += wg_W2[j * 32 + k] * wg_Wg[k * 64 + n];
            Wc2[i] = acc;
        } else {
            int n = i - 2048;
            float acc = 0.f;
            #pragma unroll 8
            for (int k = 0; k < 32; ++k) acc += wg_b2[k] * wg_Wg[k * 64 + n];
            bc2[n] = acc + wg_bg[n];
        }
    }
}

// ============================================================================
// K1: S = [skip | elu(h1)] = flat @ [Ws|W1] + [bs|b1], M=32768 K=2048 N=64.
// (unchanged from R1 — passed; profile next round will show if it dominates)
// ============================================================================
__launch_bounds__(256, 4)
__global__ void k1_wgemm(const float* __restrict__ x, const unsigned short* __restrict__ WcombT,
                         const float* __restrict__ wg_bs, const float* __restrict__ wg_b1,
                         float* __restrict__ S) {
    __shared__ float Cbuf[4 * 64 * 33];
    int tid  = threadIdx.x;
    int wv   = tid >> 6;
    int lane = tid & 63;
    int l31  = lane & 31, s = lane >> 5;
    int tile = blockIdx.x;
    long tok = (long)tile * 32 + l31;

    const float*          xrow = x + tok * VI + wv * 512 + s * 8;
    const unsigned short* a0p  = WcombT + (l31)      * 2048 + wv * 512 + s * 8;
    const unsigned short* a1p  = WcombT + (l31 + 32) * 2048 + wv * 512 + s * 8;

    floatx16 acc0 = {}; floatx16 acc1 = {};
    #pragma unroll 4
    for (int ks = 0; ks < 32; ++ks) {
        int ko = ks * 16;
        short8 af0 = *(const short8*)(a0p + ko);
        short8 af1 = *(const short8*)(a1p + ko);
        float4 xa = *(const float4*)(xrow + ko);
        float4 xb = *(const float4*)(xrow + ko + 4);
        union { unsigned u[4]; short8 s8; } bp;
        bp.u[0] = pk2bf(xa.x, xa.y);
        bp.u[1] = pk2bf(xa.z, xa.w);
        bp.u[2] = pk2bf(xb.x, xb.y);
        bp.u[3] = pk2bf(xb.z, xb.w);
        acc0 = MFMA32(af0, bp.s8, acc0);
        acc1 = MFMA32(af1, bp.s8, acc1);
    }
    float* cb = Cbuf + wv * (64 * 33);
    #pragma unroll
    for (int reg = 0; reg < 16; ++reg) {
        int r0 = (reg & 3) + 8 * (reg >> 2) + 4 * s;
        cb[(r0)*33 + l31]      = acc0[reg];
        cb[(r0 + 32)*33 + l31] = acc1[reg];
    }
    __syncthreads();
    int n  = tid & 63;
    int tb = (tid >> 6) * 8;
    #pragma unroll
    for (int g = 0; g < 8; ++g) {
        int t = tb + g;
        float v = Cbuf[0*2112 + n*33 + t] + Cbuf[1*2112 + n*33 + t]
                + Cbuf[2*2112 + n*33 + t] + Cbuf[3*2112 + n*33 + t];
        if (n < 32) v += wg_bs[n];
        else        v = elu1(v + wg_b1[n - 32]);
        S[((long)tile * 32 + t) * 64 + n] = v;
    }
}

// ============================================================================
// K2: per-token z = h1e@Wc2 + bc2 (folded) ; w = softmax(LN(skip+glu(z)))
// ============================================================================
__launch_bounds__(256, 4)
__global__ void k2_token(const float* __restrict__ S,
                         const float* __restrict__ Wc2, const float* __restrict__ bc2,
                         const float* __restrict__ wg_gamma, const float* __restrict__ wg_beta,
                         float* __restrict__ wout) {
    int tid = threadIdx.x;
    int wv = tid >> 6, lane = tid & 63;
    int l31 = lane & 31;
    long t = (long)blockIdx.x * 4 + wv;
    float sv = S[t * 64 + lane];
    // z[lane] over 64 outputs, K=32 (folded)
    float z = bc2[lane];
    #pragma unroll
    for (int k = 0; k < 32; ++k) {
        float hk = __shfl(sv, 32 + k);
        z += hk * Wc2[k * 64 + lane];
    }
    float za   = __shfl(z, l31);
    float zg   = __shfl(z, l31 + 32);
    float skip = __shfl(sv, l31);
    float y = skip + za / (1.f + __expf(-zg));
    float s1 = y;
    #pragma unroll
    for (int m = 1; m <= 16; m <<= 1) s1 += __shfl_xor(s1, m);
    float mean = s1 * (1.f / 32.f);
    float d = y - mean;
    float s2 = d * d;
    #pragma unroll
    for (int m = 1; m <= 16; m <<= 1) s2 += __shfl_xor(s2, m);
    float rinv  = rsqrtf(s2 * (1.f / 32.f) + 1e-5f);
    float logit = d * rinv * wg_gamma[l31] + wg_beta[l31];
    float mx = logit;
    #pragma unroll
    for (int m = 1; m <= 16; m <<= 1) mx = fmaxf(mx, __shfl_xor(mx, m));
    float e = __expf(logit - mx);
    float se = e;
    #pragma unroll
    for (int m = 1; m <= 16; m <<= 1) se += __shfl_xor(se, m);
    if (lane < 32) wout[t * 32 + lane] = e / se;
}

// ============================================================================
// K3: per-variable GRNs + weighted combine. Folded (h1 -> g directly).
// Block: 128 tokens x 8 vars (v-loop), grid = 4 vgroups x 256 token-blocks.
// x staged bf16 (LDS 52.7 KB total -> 3 blocks/CU). Skip recovered from the
// bf16 B-frags via shfl_xor(32) half-swap (no LDS gather).
// ============================================================================
static __device__ __forceinline__ void tile_to_bfrags(const float* t16, int sh,
                                                      short8* f0, short8* f1) {
    unsigned P[8];
    #pragma unroll
    for (int i = 0; i < 8; ++i) P[i] = pk2bf(t16[2 * i], t16[2 * i + 1]);
    unsigned X[8];
    #pragma unroll
    for (int i = 0; i < 8; ++i) X[i] = (unsigned)__shfl_xor((int)P[i], 32);
    union { unsigned u[4]; short8 s8; } a, b;
    a.u[0] = sh ? X[2] : P[0];  a.u[1] = sh ? X[3] : P[1];
    a.u[2] = sh ? P[2] : X[0];  a.u[3] = sh ? P[3] : X[1];
    b.u[0] = sh ? X[6] : P[4];  b.u[1] = sh ? X[7] : P[5];
    b.u[2] = sh ? P[6] : X[4];  b.u[3] = sh ? P[7] : X[5];
    *f0 = a.s8; *f1 = b.s8;
}

__launch_bounds__(256, 3)
__global__ void k3_vgrn(const float* __restrict__ x, const unsigned short* __restrict__ wAv,
                        const float* __restrict__ v_gamma, const float* __restrict__ v_beta,
                        const float* __restrict__ wbuf, float* __restrict__ out) {
    __shared__ __align__(16) unsigned short wA[192 * 88];   // 33,792 B
    __shared__ __align__(16) unsigned short xt[128 * 72];   // 18,432 B (stride 72: 16B-aligned)
    __shared__ float gb[128];
    int tid  = threadIdx.x;
    int wv   = tid >> 6, lane = tid & 63;
    int l31  = lane & 31, s = lane >> 5;
    int vg   = blockIdx.x & 3;          // 4 vgroups of 8 vars
    int tb   = blockIdx.x >> 2;         // 256 token-blocks of 128
    int tl   = wv * 32 + l31;
    long tokg = (long)tb * 128 + tl;

    float outacc[32];
    #pragma unroll
    for (int i = 0; i < 32; ++i) outacc[i] = 0.f;

    union { unsigned u[4]; short8 s8; } onef;
    onef.u[0] = (s == 0) ? 0x00003F80u : 0u;
    onef.u[1] = 0; onef.u[2] = 0; onef.u[3] = 0;

    const unsigned short* wArow = wA + l31 * 88 + s * 8;
    int srow = tid >> 1, shalf = tid & 1;   // x staging role

    for (int j8 = 0; j8 < 8; ++j8) {
        int v = vg * 8 + j8;
        __syncthreads();   // protect LDS vs previous iteration's readers
        // ---- stage weights: 192x88 bf16 = 2112 uint4 from hot L2 ----
        {
            const uint4* src = (const uint4*)(wAv + (long)v * 16896);
            uint4* dst = (uint4*)wA;
            for (int c = tid; c < 2112; c += 256) dst[c] = src[c];
        }
        // ---- stage x tile as bf16: 2 threads per token row ----
        {
            const float* xs = x + ((long)tb * 128 + srow) * VI + v * 64 + shalf * 32;
            unsigned short* xd = xt + srow * 72 + shalf * 32;
            #pragma unroll
            for (int q = 0; q < 4; ++q) {
                float4 a = ((const float4*)xs)[2 * q];
                float4 b = ((const float4*)xs)[2 * q + 1];
                uint4 w;
                w.x = pk2bf(a.x, a.y); w.y = pk2bf(a.z, a.w);
                w.z = pk2bf(b.x, b.y); w.w = pk2bf(b.z, b.w);
                ((uint4*)xd)[q] = w;
            }
        }
        if (tid < 128) {
            int h = tid >> 1;
            gb[tid] = (tid & 1) ? v_beta[v * 64 + h] : v_gamma[v * 64 + h];
        }
        __syncthreads();

        // ---- x B-frags: raw ds_read_b128 ----
        union { short8 s8; unsigned u[4]; } xb[4];
        #pragma unroll
        for (int ks = 0; ks < 4; ++ks)
            xb[ks].s8 = *(const short8*)(xt + tl * 72 + ks * 16 + s * 8);

        // ---- H1T = W1a @ [XT;1] ----
        floatx16 h1a0 = {}, h1a1 = {};
        #pragma unroll
        for (int ks = 0; ks < 5; ++ks) {
            short8 b = (ks < 4) ? xb[ks].s8 : onef.s8;
            h1a0 = MFMA32(*(const short8*)(wArow + 0    + ks * 16), b, h1a0);
            h1a1 = MFMA32(*(const short8*)(wArow + 2816 + ks * 16), b, h1a1);
        }
        short8 h1b[4];
        {
            float t16[16];
            #pragma unroll
            for (int r = 0; r < 16; ++r) t16[r] = elu1(h1a0[r]);
            tile_to_bfrags(t16, s, &h1b[0], &h1b[1]);
            #pragma unroll
            for (int r = 0; r < 16; ++r) t16[r] = elu1(h1a1[r]);
            tile_to_bfrags(t16, s, &h1b[2], &h1b[3]);
        }
        // ---- GT = Wca @ [H1T;1]  (FOLDED: rows 0..63 = a, 64..127 = gate) ----
        floatx16 g0 = {}, g1 = {}, g2 = {}, g3 = {};
        #pragma unroll
        for (int ks = 0; ks < 5; ++ks) {
            short8 b = (ks < 4) ? h1b[ks] : onef.s8;
            g0 = MFMA32(*(const short8*)(wArow + 2 * 2816 + ks * 16), b, g0);
            g1 = MFMA32(*(const short8*)(wArow + 3 * 2816 + ks * 16), b, g1);
            g2 = MFMA32(*(const short8*)(wArow + 4 * 2816 + ks * 16), b, g2);
            g3 = MFMA32(*(const short8*)(wArow + 5 * 2816 + ks * 16), b, g3);
        }
        // ---- skip extraction from xb frags (half-swap via shfl_xor 32) ----
        unsigned ownu[4][2], Xu[4][2];
        #pragma unroll
        for (int kk = 0; kk < 4; ++kk) {
            #pragma unroll
            for (int d = 0; d < 2; ++d) {
                ownu[kk][d] = s ? xb[kk].u[2 + d] : xb[kk].u[d];
                unsigned R  = s ? xb[kk].u[d]     : xb[kk].u[2 + d];
                Xu[kk][d]   = (unsigned)__shfl_xor((int)R, 32);
            }
        }
        // ---- glu + skip + LN + weighted combine ----
        float y[32];
        #pragma unroll
        for (int r = 0; r < 16; ++r) {
            int a = r >> 2, b_ = r & 3, d = b_ >> 1, kk = a >> 1;
            bool odd = (a & 1);
            unsigned v0 = odd ? (s ? ownu[kk][d]     : Xu[kk][d])
                              : (s ? Xu[kk][d]       : ownu[kk][d]);
            unsigned v1 = odd ? (s ? ownu[2+kk][d]   : Xu[2+kk][d])
                              : (s ? Xu[2+kk][d]     : ownu[2+kk][d]);
            float sk0 = (b_ & 1) ? bfhi(v0) : bflo(v0);
            float sk1 = (b_ & 1) ? bfhi(v1) : bflo(v1);
            y[r]      = sk0 + g0[r] / (1.f + __expf(-g2[r]));
            y[16 + r] = sk1 + g1[r] / (1.f + __expf(-g3[r]));
        }
        float s1 = 0.f;
        #pragma unroll
        for (int i = 0; i < 32; ++i) s1 += y[i];
        s1 += __shfl_xor(s1, 32);
        float mean = s1 * (1.f / 64.f);
        float s2 = 0.f;
        #pragma unroll
        for (int i = 0; i < 32; ++i) { float d = y[i] - mean; s2 += d * d; }
        s2 += __shfl_xor(s2, 32);
        float rinv = rsqrtf(s2 * (1.f / 64.f) + 1e-5f);
        float wvv = wbuf[tokg * 32 + v];
        #pragma unroll
        for (int r = 0; r < 16; ++r) {
            int hr = (r & 3) + 8 * (r >> 2) + 4 * s;
            float pv0 = (y[r]      - mean) * rinv * gb[2*hr]      + gb[2*hr + 1];
            float pv1 = (y[16 + r] - mean) * rinv * gb[2*(hr+32)] + gb[2*(hr+32) + 1];
            outacc[r]      += wvv * pv0;
            outacc[16 + r] += wvv * pv1;
        }
    }
    // ---- combine across 4 vgroups via atomics ----
    #pragma unroll
    for (int r = 0; r < 16; ++r) {
        int hr = (r & 3) + 8 * (r >> 2) + 4 * s;
        atomicAdd(out + tokg * 64 + hr,      outacc[r]);
        atomicAdd(out + tokg * 64 + 32 + hr, outacc[16 + r]);
    }
}

// ============================================================================
extern "C" void kernel_launch(void* const* d_in, const int* in_sizes, int n_in,
                              void* d_out, int out_size, void* d_ws, size_t ws_size,
                              hipStream_t stream) {
    const float* x        = (const float*)d_in[0];
    const float* wg_W1    = (const float*)d_in[1];
    const float* wg_b1    = (const float*)d_in[2];
    const float* wg_W2    = (const float*)d_in[3];
    const float* wg_b2    = (const float*)d_in[4];
    const float* wg_Wg    = (const float*)d_in[5];
    const float* wg_bg    = (const float*)d_in[6];
    const float* wg_Ws    = (const float*)d_in[7];
    const float* wg_bs    = (const float*)d_in[8];
    const float* wg_gamma = (const float*)d_in[9];
    const float* wg_beta  = (const float*)d_in[10];
    const float* v_W1     = (const float*)d_in[11];
    const float* v_b1     = (const float*)d_in[12];
    const float* v_W2     = (const float*)d_in[13];
    const float* v_b2     = (const float*)d_in[14];
    const float* v_Wg     = (const float*)d_in[15];
    const float* v_bg     = (const float*)d_in[16];
    const float* v_gamma  = (const float*)d_in[17];
    const float* v_beta   = (const float*)d_in[18];
    (void)in_sizes; (void)n_in; (void)ws_size;

    char* ws = (char*)d_ws;
    float* S               = (float*)(ws + WS_S);
    float* wbuf            = (float*)(ws + WS_WBUF);
    unsigned short* WcombT = (unsigned short*)(ws + WS_WCOMBT);
    unsigned short* wAv    = (unsigned short*)(ws + WS_WAV);
    float* Wc2             = (float*)(ws + WS_WC2);
    float* bc2             = (float*)(ws + WS_BC2);
    float* out             = (float*)d_out;

    hipMemsetAsync(d_out, 0, (size_t)out_size * sizeof(float), stream);
    k0_prep<<<512, 256, 0, stream>>>(wg_W1, wg_Ws, wg_W2, wg_b2, wg_Wg, wg_bg,
                                     v_W1, v_b1, v_W2, v_b2, v_Wg, v_bg,
                                     WcombT, wAv, Wc2, bc2);
    k1_wgemm<<<1024, 256, 0, stream>>>(x, WcombT, wg_bs, wg_b1, S);
    k2_token<<<8192, 256, 0, stream>>>(S, Wc2, bc2, wg_gamma, wg_beta, wbuf);
    k3_vgrn<<<1024, 256, 0, stream>>>(x, wAv, v_gamma, v_beta, wbuf, out);
}